// Round 9
// baseline (6432.434 us; speedup 1.0000x reference)
//
#include <hip/hip_runtime.h>
#include <stdint.h>

#define TT 128
#define BB 128
#define NN 1024

// World model (R6 probe + reference-source dtype analysis):
//   tx: PACKED BF16 storage (the dataset's bf16 tensor; runtime-probed),
//   W : f32 storage, bf16-rounded values (bf16 round-trip cast),
//   b : full-precision f32,
//   out: FLOAT32 (jax promotion: bf16 tx + f32 gemm + f32 b -> f32 carry),
//   np ref: float32 numpy, y @ W.T via OpenBLAS sgemm (kc=384 K-panels,
//           sequential-k single accumulator within each panel,
//           C = ((P0 + P1) + P2)).
// With binary y every product is exact, so emulating that association
// reproduces the reference trajectory BIT-EXACTLY in f32.

__device__ __forceinline__ float bf2f(uint16_t u) {
  union { uint32_t i; float f; } c;
  c.i = ((uint32_t)u) << 16;
  return c.f;
}

// ---------------------------------------------------------------------------
// Kernel 0: IN-PLACE transpose of f32 W [1024][1024] (tile-pair swap).
// After: W[k*1024+n] == Worig[n][k].  Harness restores d_in every launch.
// ---------------------------------------------------------------------------
__global__ __launch_bounds__(256) void w_transpose_inplace(float* __restrict__ W) {
  __shared__ float ta[32][33];
  __shared__ float tb[32][33];

  int rem = blockIdx.x;
  int I = 0;
  while (rem >= (32 - I)) { rem -= (32 - I); ++I; }
  const int J = I + rem;

  const int lx = threadIdx.x & 31;
  const int ly = threadIdx.x >> 5;  // 0..7

  if (I == J) {
#pragma unroll
    for (int i = 0; i < 4; ++i)
      ta[ly + i * 8][lx] = W[(I * 32 + ly + i * 8) * NN + J * 32 + lx];
    __syncthreads();
#pragma unroll
    for (int i = 0; i < 4; ++i)
      W[(I * 32 + ly + i * 8) * NN + J * 32 + lx] = ta[lx][ly + i * 8];
  } else {
#pragma unroll
    for (int i = 0; i < 4; ++i) {
      ta[ly + i * 8][lx] = W[(I * 32 + ly + i * 8) * NN + J * 32 + lx];
      tb[ly + i * 8][lx] = W[(J * 32 + ly + i * 8) * NN + I * 32 + lx];
    }
    __syncthreads();
#pragma unroll
    for (int i = 0; i < 4; ++i) {
      W[(J * 32 + ly + i * 8) * NN + I * 32 + lx] = ta[lx][ly + i * 8];
      W[(I * 32 + ly + i * 8) * NN + J * 32 + lx] = tb[lx][ly + i * 8];
    }
  }
}

// ---------------------------------------------------------------------------
// Kernel 1: per-sample LIF, FLOAT32, OpenBLAS-sgemm association for the
// recurrent term: K split into panels [0,384),[384,768),[768,1024)
// (aligning with packed-word groups g in [0,96),[96,192),[192,256));
// each panel summed sequentially in increasing k into its own accumulator,
// then a = (P0 + P1) + P2.  x = (tx + a) + b ;  v = (y?0:0.5f*v)+x ;
// y = v > 0.5f.  One workgroup per sample, 256 threads x 4 neurons.
// OUTPUT: f32 (1.0f / 0.0f).  tx storage probed at runtime.
// ---------------------------------------------------------------------------
__global__ __launch_bounds__(256) void lif_persample_f32(
    const void* __restrict__ tx_raw, const float* __restrict__ bias,
    const float* __restrict__ Wt, float* __restrict__ out) {
  const int b = blockIdx.x;
  const int tid = threadIdx.x;

  __shared__ uint32_t act32[256];
  __shared__ int scount;

  // ---- runtime tx-storage probe ----
  // bits[14:7] of each u32 word: packed-bf16 N(0,1) -> bf16 exponent in
  // [0x74,0x81) ~99.8% of words; f32 storage (mantissa bits, or zero for
  // bf16-valued f32) -> <6%. 2048 words sampled; uniform across blocks.
  if (tid == 0) scount = 0;
  __syncthreads();
  {
    const uint32_t* txw = (const uint32_t*)tx_raw;
    int local = 0;
#pragma unroll
    for (int i = 0; i < 8; ++i) {
      const uint32_t f = (txw[tid * 8 + i] >> 7) & 0xFFu;
      local += (f >= 0x74u && f < 0x81u) ? 1 : 0;
    }
    atomicAdd(&scount, local);
  }
  __syncthreads();
  const bool tx_is_bf16 = (scount > 1024);

  const float4* __restrict__ W4 = (const float4*)Wt;   // row k at W4[k*256+tid]
  const float4* __restrict__ txf = (const float4*)tx_raw;
  const ushort4* __restrict__ txh = (const ushort4*)tx_raw;
  float4* __restrict__ out4 = (float4*)out;

  const float4 b4 = ((const float4*)bias)[tid];

  float v0 = 0.0f, v1 = 0.0f, v2 = 0.0f, v3 = 0.0f;  // membrane (REST = 0)
  int y0 = 0, y1 = 0, y2 = 0, y3 = 0;                // previous spikes

  act32[tid] = 0u;  // t=0: no previous spikes
  __syncthreads();

  for (int t = 0; t < TT; ++t) {
    // ---- recurrent gather: three kc=384-aligned panels, each summed
    //      sequentially (increasing k) into its own f32 accumulator ----
    float a0, a1, a2, a3;
    {
      float p0 = 0.f, p1 = 0.f, p2 = 0.f, p3 = 0.f;   // panel accumulators
      float q0 = 0.f, q1 = 0.f, q2 = 0.f, q3 = 0.f;
      float r0 = 0.f, r1 = 0.f, r2 = 0.f, r3 = 0.f;
#define GATHER(G0, G1, A0, A1, A2, A3)                                   \
      for (int g = (G0); g < (G1); ++g) {                                \
        const uint32_t f = act32[g];                                     \
        if (f) {                                                         \
          const float4* row = &W4[g * 1024 + tid];                       \
          if (f & 0x000000ffu) {                                         \
            const float4 w = row[0];                                     \
            A0 += w.x; A1 += w.y; A2 += w.z; A3 += w.w;                  \
          }                                                              \
          if (f & 0x0000ff00u) {                                         \
            const float4 w = row[256];                                   \
            A0 += w.x; A1 += w.y; A2 += w.z; A3 += w.w;                  \
          }                                                              \
          if (f & 0x00ff0000u) {                                         \
            const float4 w = row[512];                                   \
            A0 += w.x; A1 += w.y; A2 += w.z; A3 += w.w;                  \
          }                                                              \
          if (f & 0xff000000u) {                                         \
            const float4 w = row[768];                                   \
            A0 += w.x; A1 += w.y; A2 += w.z; A3 += w.w;                  \
          }                                                              \
        }                                                                \
      }
      GATHER(0,   96,  p0, p1, p2, p3)   // k in [0,   384)
      GATHER(96,  192, q0, q1, q2, q3)   // k in [384, 768)
      GATHER(192, 256, r0, r1, r2, r3)   // k in [768, 1024)
#undef GATHER
      a0 = (p0 + q0) + r0;
      a1 = (p1 + q1) + r1;
      a2 = (p2 + q2) + r2;
      a3 = (p3 + q3) + r3;
    }

    // ---- input load (storage-probed), LIF update in f32, ref op order ----
    const int off = (t * BB + b) * 256 + tid;
    float xx0, xx1, xx2, xx3;
    if (tx_is_bf16) {
      const ushort4 xu = txh[off];
      xx0 = bf2f(xu.x); xx1 = bf2f(xu.y); xx2 = bf2f(xu.z); xx3 = bf2f(xu.w);
    } else {
      const float4 x4 = txf[off];
      xx0 = x4.x; xx1 = x4.y; xx2 = x4.z; xx3 = x4.w;
    }
    const float xv0 = (xx0 + a0) + b4.x;
    const float xv1 = (xx1 + a1) + b4.y;
    const float xv2 = (xx2 + a2) + b4.z;
    const float xv3 = (xx3 + a3) + b4.w;
    v0 = (y0 ? 0.0f : 0.5f * v0) + xv0;
    v1 = (y1 ? 0.0f : 0.5f * v1) + xv1;
    v2 = (y2 ? 0.0f : 0.5f * v2) + xv2;
    v3 = (y3 ? 0.0f : 0.5f * v3) + xv3;
    y0 = (v0 > 0.5f);
    y1 = (v1 > 0.5f);
    y2 = (v2 > 0.5f);
    y3 = (v3 > 0.5f);

    // ---- publish spikes for next step ----
    __syncthreads();  // all gathers done before overwrite
    act32[tid] = (uint32_t)y0 | ((uint32_t)y1 << 8) |
                 ((uint32_t)y2 << 16) | ((uint32_t)y3 << 24);
    __syncthreads();  // new act32 visible

    // ---- FLOAT32 output ----
    float4 o;
    o.x = y0 ? 1.0f : 0.0f;
    o.y = y1 ? 1.0f : 0.0f;
    o.z = y2 ? 1.0f : 0.0f;
    o.w = y3 ? 1.0f : 0.0f;
    out4[off] = o;
  }
}

extern "C" void kernel_launch(void* const* d_in, const int* in_sizes, int n_in,
                              void* d_out, int out_size, void* d_ws, size_t ws_size,
                              hipStream_t stream) {
  // Identify inputs by element count:
  //   tx = 128*128*1024 (packed bf16, runtime-verified), W = 1024*1024 (f32,
  //   bf16-valued), b = 1024 (f32).
  const void* tx = nullptr;
  float* W = nullptr;
  const float* bs = nullptr;
  for (int i = 0; i < n_in; ++i) {
    if (in_sizes[i] == TT * BB * NN) tx = d_in[i];
    else if (in_sizes[i] == NN * NN) W = (float*)d_in[i];
    else if (in_sizes[i] == NN) bs = (const float*)d_in[i];
  }
  float* out = (float*)d_out;  // [T, B, N] f32 spikes

  w_transpose_inplace<<<dim3(528), dim3(256), 0, stream>>>(W);
  lif_persample_f32<<<dim3(BB), dim3(256), 0, stream>>>(tx, bs, W, out);
}

// Round 10
// 2217.595 us; speedup vs baseline: 2.9006x; 2.9006x over previous
//
#include <hip/hip_runtime.h>
#include <stdint.h>

#define TT 128
#define BB 128
#define NN 1024

// World model (verified bit-exact in R9):
//   tx: packed bf16 storage (runtime-probed each launch; probe also handles f32),
//   W : f32 storage, bf16-rounded values; b: f32; out: f32.
//   Reference recurrent sum: OpenBLAS sgemm kc=384 panels, sequential-k
//   single accumulator per panel, a = (P0 + P1) + P2.  With binary y all
//   products are exact, so this association is reproduced exactly.

__device__ __forceinline__ float bfbits2f(uint32_t lo16) {
  union { uint32_t i; float f; } c;
  c.i = lo16 << 16;
  return c.f;
}

// ---------------------------------------------------------------------------
// Kernel 0: in-place f32 transpose of W (tile-pair swap)  +  bf16 repack of
// W^T into ws  +  losslessness check (dirty flag set if any f32 word has
// nonzero low 16 bits — then the gather kernel uses the f32 path).
// ---------------------------------------------------------------------------
__global__ __launch_bounds__(256) void w_transpose_repack(
    float* __restrict__ W, uint16_t* __restrict__ WtBf,
    uint32_t* __restrict__ dirty) {
  __shared__ float ta[32][33];
  __shared__ float tb[32][33];

  int rem = blockIdx.x;
  int I = 0;
  while (rem >= (32 - I)) { rem -= (32 - I); ++I; }
  const int J = I + rem;

  const int lx = threadIdx.x & 31;
  const int ly = threadIdx.x >> 5;  // 0..7
  uint32_t bad = 0;

  if (I == J) {
#pragma unroll
    for (int i = 0; i < 4; ++i)
      ta[ly + i * 8][lx] = W[(I * 32 + ly + i * 8) * NN + J * 32 + lx];
    __syncthreads();
#pragma unroll
    for (int i = 0; i < 4; ++i) {
      const int idx = (I * 32 + ly + i * 8) * NN + J * 32 + lx;
      const float v = ta[lx][ly + i * 8];
      const uint32_t bits = __float_as_uint(v);
      W[idx] = v;
      WtBf[idx] = (uint16_t)(bits >> 16);
      bad |= (bits & 0xFFFFu);
    }
  } else {
#pragma unroll
    for (int i = 0; i < 4; ++i) {
      ta[ly + i * 8][lx] = W[(I * 32 + ly + i * 8) * NN + J * 32 + lx];
      tb[ly + i * 8][lx] = W[(J * 32 + ly + i * 8) * NN + I * 32 + lx];
    }
    __syncthreads();
#pragma unroll
    for (int i = 0; i < 4; ++i) {
      const int idxA = (J * 32 + ly + i * 8) * NN + I * 32 + lx;
      const float va = ta[lx][ly + i * 8];
      const uint32_t bitsA = __float_as_uint(va);
      W[idxA] = va;
      WtBf[idxA] = (uint16_t)(bitsA >> 16);
      bad |= (bitsA & 0xFFFFu);

      const int idxB = (I * 32 + ly + i * 8) * NN + J * 32 + lx;
      const float vb = tb[lx][ly + i * 8];
      const uint32_t bitsB = __float_as_uint(vb);
      W[idxB] = vb;
      WtBf[idxB] = (uint16_t)(bitsB >> 16);
      bad |= (bitsB & 0xFFFFu);
    }
  }
  const unsigned long long bm = __ballot(bad != 0);
  if ((threadIdx.x & 63) == 0 && bm) atomicOr(dirty, 1u);
}

// ---------------------------------------------------------------------------
// Kernel 1: per-sample LIF, 1024 threads (1 neuron/thread, 16 waves/CU).
// Per step: ballot-compacted active list (globally sorted ascending k by
// construction: lane order within wave + ascending wave bases), then flat
// unroll-8 gather over three kc=384-aligned panel segments, sequential f32
// adds in k order (bit-identical to R9's verified association).
// ---------------------------------------------------------------------------
__global__ __launch_bounds__(1024) void lif_persample(
    const void* __restrict__ tx_raw, const float* __restrict__ bias,
    const float* __restrict__ WtF32, const uint16_t* __restrict__ WtBf,
    const uint32_t* __restrict__ dirty, float* __restrict__ out) {
  const int b = blockIdx.x;
  const int tid = threadIdx.x;     // == neuron index n == recurrent index k
  const int lane = tid & 63;
  const int wv = tid >> 6;         // 0..15

  __shared__ uint16_t lst[NN];
  __shared__ int wcnt[16];
  __shared__ int sprobe;

  // ---- runtime tx-storage probe (bf16-packed vs f32), as verified in R9 ----
  if (tid == 0) sprobe = 0;
  __syncthreads();
  {
    const uint32_t* txw = (const uint32_t*)tx_raw;
    int local = 0;
#pragma unroll
    for (int i = 0; i < 2; ++i) {
      const uint32_t f = (txw[tid * 2 + i] >> 7) & 0xFFu;
      local += (f >= 0x74u && f < 0x81u) ? 1 : 0;
    }
    atomicAdd(&sprobe, local);
  }
  __syncthreads();
  const bool tx_is_bf16 = (sprobe > 1024);   // of 2048 sampled words
  const bool w_bf = (*dirty == 0u);          // bf16 repack lossless?

  const uint16_t* __restrict__ txh = (const uint16_t*)tx_raw;
  const float* __restrict__ txf = (const float*)tx_raw;
  const float bz = bias[tid];

  float v = 0.0f;   // membrane (REST = 0)
  int y = 0;        // previous spike

  // sequential gather over lst[s,e): ascending k, ONE accumulator (exact
  // reference association). Loads batched 8-wide for ILP; adds in order.
  auto gather = [&](int s, int e) -> float {
    float acc = 0.0f;
    int i = s;
    if (w_bf) {
      for (; i + 8 <= e; i += 8) {
        float w[8];
#pragma unroll
        for (int u = 0; u < 8; ++u) {
          const int k = __builtin_amdgcn_readfirstlane((int)lst[i + u]);
          w[u] = bfbits2f((uint32_t)WtBf[k * NN + tid]);
        }
#pragma unroll
        for (int u = 0; u < 8; ++u) acc += w[u];
      }
      for (; i < e; ++i) {
        const int k = __builtin_amdgcn_readfirstlane((int)lst[i]);
        acc += bfbits2f((uint32_t)WtBf[k * NN + tid]);
      }
    } else {
      for (; i + 8 <= e; i += 8) {
        float w[8];
#pragma unroll
        for (int u = 0; u < 8; ++u) {
          const int k = __builtin_amdgcn_readfirstlane((int)lst[i + u]);
          w[u] = WtF32[k * NN + tid];
        }
#pragma unroll
        for (int u = 0; u < 8; ++u) acc += w[u];
      }
      for (; i < e; ++i) {
        const int k = __builtin_amdgcn_readfirstlane((int)lst[i]);
        acc += WtF32[k * NN + tid];
      }
    }
    return acc;
  };

  for (int t = 0; t < TT; ++t) {
    // ---- build compacted active list (ascending k) ----
    const unsigned long long m = __ballot(y);
    if (lane == 0) wcnt[wv] = __popcll(m);
    __syncthreads();  // SYNC1: wcnt visible (also: prior gather reads done)
    int base = 0, c0 = 0, c01 = 0, ctot = 0;
#pragma unroll
    for (int w = 0; w < 16; ++w) {
      const int c = wcnt[w];
      base += (w < wv) ? c : 0;
      c0   += (w < 6)  ? c : 0;   // panel 0: k in [0, 384)   (waves 0..5)
      c01  += (w < 12) ? c : 0;   // panels 0+1: k < 768      (waves 0..11)
      ctot += c;
    }
    if (y) {
      const int below = __builtin_amdgcn_mbcnt_hi(
          (uint32_t)(m >> 32), __builtin_amdgcn_mbcnt_lo((uint32_t)m, 0));
      lst[base + below] = (uint16_t)tid;
    }
    __syncthreads();  // SYNC2: lst complete

    // ---- recurrent term: (P0 + P1) + P2, sequential k within panels ----
    const float p = gather(0, c0);
    const float q = gather(c0, c01);
    const float r = gather(c01, ctot);
    const float a = (p + q) + r;

    // ---- LIF update, reference op order, f32 ----
    const int off = (t * BB + b) * NN + tid;
    const float xx = tx_is_bf16 ? bfbits2f((uint32_t)txh[off]) : txf[off];
    const float xv = (xx + a) + bz;
    v = (y ? 0.0f : 0.5f * v) + xv;
    y = (v > 0.5f);

    out[off] = y ? 1.0f : 0.0f;
    __syncthreads();  // SYNC3: all lst reads done before next step's writes
  }
}

extern "C" void kernel_launch(void* const* d_in, const int* in_sizes, int n_in,
                              void* d_out, int out_size, void* d_ws, size_t ws_size,
                              hipStream_t stream) {
  // Inputs by element count: tx = 128*128*1024 (bf16-packed),
  // W = 1024*1024 (f32, bf16-valued), b = 1024 (f32).
  const void* tx = nullptr;
  float* W = nullptr;
  const float* bs = nullptr;
  for (int i = 0; i < n_in; ++i) {
    if (in_sizes[i] == TT * BB * NN) tx = d_in[i];
    else if (in_sizes[i] == NN * NN) W = (float*)d_in[i];
    else if (in_sizes[i] == NN) bs = (const float*)d_in[i];
  }
  float* out = (float*)d_out;                     // [T, B, N] f32 spikes

  uint16_t* WtBf = (uint16_t*)d_ws;               // 2 MB bf16 W^T
  uint32_t* dirty = (uint32_t*)((char*)d_ws + 2u * 1024u * 1024u);

  // ws is poisoned 0xAA each launch — clear the dirty flag first.
  hipMemsetAsync(dirty, 0, sizeof(uint32_t), stream);

  w_transpose_repack<<<dim3(528), dim3(256), 0, stream>>>(W, WtBf, dirty);
  lif_persample<<<dim3(BB), dim3(1024), 0, stream>>>(tx, bs, W, WtBf, dirty, out);
}